// Round 4
// baseline (1376.581 us; speedup 1.0000x reference)
//
#include <hip/hip_runtime.h>
#include <hip/hip_bf16.h>
#include <math.h>

#define N_NODES 100000
#define N_EDGES 800000
#define IN_C 96
#define OUT_C 64
#define NPB 64   // nodes per block in linear kernel

// ================= CSR build =================

__global__ void zero_int_kernel(int* __restrict__ p, int n) {
    int i = blockIdx.x * blockDim.x + threadIdx.x;
    if (i < n) p[i] = 0;
}

__global__ void count_kernel(const int* __restrict__ col, int* __restrict__ cnt, int e) {
    int i = blockIdx.x * blockDim.x + threadIdx.x;
    if (i < e) atomicAdd(&cnt[col[i]], 1);
}

__global__ void dinv_kernel(const int* __restrict__ cnt, float* __restrict__ dinv, int n) {
    int i = blockIdx.x * blockDim.x + threadIdx.x;
    if (i < n) dinv[i] = rsqrtf((float)cnt[i] + 1.0f);
}

__global__ void scan_pass1_kernel(const int* __restrict__ cnt, int* __restrict__ partials, int n) {
    __shared__ int s[256];
    int i = blockIdx.x * 256 + threadIdx.x;
    int v = (i < n) ? cnt[i] : 0;
    s[threadIdx.x] = v;
    __syncthreads();
    for (int off = 128; off > 0; off >>= 1) {
        if (threadIdx.x < off) s[threadIdx.x] += s[threadIdx.x + off];
        __syncthreads();
    }
    if (threadIdx.x == 0) partials[blockIdx.x] = s[0];
}

__global__ void scan_pass2_kernel(int* __restrict__ partials, int* __restrict__ row_start,
                                  int nparts, int n_nodes) {
    __shared__ int s[512];
    int t = threadIdx.x;
    int v = (t < nparts) ? partials[t] : 0;
    s[t] = v;
    __syncthreads();
    for (int off = 1; off < 512; off <<= 1) {
        int tmp = (t >= off) ? s[t - off] : 0;
        __syncthreads();
        s[t] += tmp;
        __syncthreads();
    }
    if (t < nparts) partials[t] = s[t] - v;
    if (t == 511) row_start[n_nodes] = s[511];
}

__global__ void scan_pass3_kernel(const int* __restrict__ cnt, const int* __restrict__ partials,
                                  int* __restrict__ row_start, int* __restrict__ cursor, int n) {
    __shared__ int s[256];
    int i = blockIdx.x * 256 + threadIdx.x;
    int t = threadIdx.x;
    int v = (i < n) ? cnt[i] : 0;
    s[t] = v;
    __syncthreads();
    for (int off = 1; off < 256; off <<= 1) {
        int tmp = (t >= off) ? s[t - off] : 0;
        __syncthreads();
        s[t] += tmp;
        __syncthreads();
    }
    if (i < n) {
        int start = partials[blockIdx.x] + s[t] - v;
        row_start[i] = start;
        cursor[i] = start;
    }
}

__global__ void csr_fill_kernel(const int* __restrict__ row, const int* __restrict__ col,
                                const float* __restrict__ dinv, int* __restrict__ cursor,
                                int2* __restrict__ csr, int e) {
    int i = blockIdx.x * blockDim.x + threadIdx.x;
    if (i >= e) return;
    int r = row[i];
    int c = col[i];
    float w = dinv[r] * dinv[c];
    int pos = atomicAdd(&cursor[c], 1);
    csr[pos] = make_int2(r, __float_as_int(w));
}

// ================= linear: y0 = x @ W^T (no bias) =================
// lane = output channel. W row chunked 16 channels at a time (16 VGPRs live),
// 16 node-accumulators per thread -> ~60 VGPR, no spill. x staged in LDS,
// all LDS reads are wave-uniform broadcasts (conflict-free).

__global__ void linear_kernel(const float* __restrict__ x, const float* __restrict__ W,
                              float* __restrict__ y, int n) {
    __shared__ float xs[NPB * IN_C];   // 24 KB

    int lane = threadIdx.x & 63;
    int wv = threadIdx.x >> 6;         // wave 0..3; wave handles 16 nodes

    int node0 = blockIdx.x * NPB;

    // cooperative coalesced stage of x: 1536 float4, stride-1 LDS writes
    const float4* xg = (const float4*)(x + (size_t)node0 * IN_C);
    float4* xs4 = (float4*)xs;
    int avail4 = (n - node0) * (IN_C / 4);
    if (avail4 > NPB * (IN_C / 4)) avail4 = NPB * (IN_C / 4);
    for (int i = threadIdx.x; i < NPB * (IN_C / 4); i += 256) {
        xs4[i] = (i < avail4) ? xg[i] : make_float4(0.f, 0.f, 0.f, 0.f);
    }
    __syncthreads();

    const float4* Wrow = (const float4*)(W + (size_t)lane * IN_C);  // 24 float4, L1-resident

    float acc[16];
#pragma unroll
    for (int k = 0; k < 16; ++k) acc[k] = 0.0f;

#pragma unroll
    for (int cc = 0; cc < 6; ++cc) {               // 6 chunks x 16 channels
        float4 w0 = Wrow[cc * 4 + 0];
        float4 w1 = Wrow[cc * 4 + 1];
        float4 w2 = Wrow[cc * 4 + 2];
        float4 w3 = Wrow[cc * 4 + 3];
#pragma unroll
        for (int k = 0; k < 16; ++k) {
            const float4* xr = xs4 + (wv * 16 + k) * (IN_C / 4) + cc * 4;
            float4 x0 = xr[0], x1 = xr[1], x2 = xr[2], x3 = xr[3];
            float a = acc[k];
            a += x0.x * w0.x + x0.y * w0.y + x0.z * w0.z + x0.w * w0.w;
            a += x1.x * w1.x + x1.y * w1.y + x1.z * w1.z + x1.w * w1.w;
            a += x2.x * w2.x + x2.y * w2.y + x2.z * w2.z + x2.w * w2.w;
            a += x3.x * w3.x + x3.y * w3.y + x3.z * w3.z + x3.w * w3.w;
            acc[k] = a;
        }
    }

#pragma unroll
    for (int k = 0; k < 16; ++k) {
        int node = node0 + wv * 16 + k;
        if (node < n) y[(size_t)node * OUT_C + lane] = acc[k];
    }
}

// ================= gather hop: one wave per node, lane = channel =================

template <bool FINAL>
__global__ void gather_kernel(const float* __restrict__ src, float* __restrict__ dst,
                              const int* __restrict__ row_start, const int2* __restrict__ csr,
                              const float* __restrict__ dinv, const float* __restrict__ bias,
                              int n) {
    int node = blockIdx.x * (blockDim.x >> 6) + (threadIdx.x >> 6);
    if (node >= n) return;
    int ch = threadIdx.x & 63;

    float s = dinv[node];
    float acc0 = s * s * src[(size_t)node * OUT_C + ch];
    float acc1 = 0.0f;

    int beg = row_start[node];
    int end = row_start[node + 1];
    int j = beg;
    for (; j + 1 < end; j += 2) {
        int2 p0 = csr[j];
        int2 p1 = csr[j + 1];
        float v0 = src[(size_t)p0.x * OUT_C + ch];
        float v1 = src[(size_t)p1.x * OUT_C + ch];
        acc0 += __int_as_float(p0.y) * v0;
        acc1 += __int_as_float(p1.y) * v1;
    }
    if (j < end) {
        int2 p = csr[j];
        acc0 += __int_as_float(p.y) * src[(size_t)p.x * OUT_C + ch];
    }
    float acc = acc0 + acc1;
    if (FINAL) {
        acc += bias[ch];
        acc = 1.0f / (1.0f + __expf(-acc));
    }
    dst[(size_t)node * OUT_C + ch] = acc;
}

// ================= launch =================

static inline size_t align16(size_t x) { return (x + 15) & ~(size_t)15; }

extern "C" void kernel_launch(void* const* d_in, const int* in_sizes, int n_in,
                              void* d_out, int out_size, void* d_ws, size_t ws_size,
                              hipStream_t stream) {
    const float* x = (const float*)d_in[0];
    const int* edge_index = (const int*)d_in[1];
    const float* W = (const float*)d_in[2];
    const float* b = (const float*)d_in[3];
    float* out = (float*)d_out;

    const int N = N_NODES;
    const int E = in_sizes[1] / 2;

    const int* row = edge_index;        // source
    const int* col = edge_index + E;    // destination

    char* ws = (char*)d_ws;
    size_t off = 0;
    int* cnt = (int*)(ws + off);        off = align16(off + (size_t)N * 4);
    float* dinv = (float*)(ws + off);   off = align16(off + (size_t)N * 4);
    int* row_start = (int*)(ws + off);  off = align16(off + (size_t)(N + 1) * 4);
    int* cursor = (int*)(ws + off);     off = align16(off + (size_t)N * 4);
    int* partials = (int*)(ws + off);   off = align16(off + 512 * 4);
    int2* csr = (int2*)(ws + off);      off = align16(off + (size_t)E * 8);
    float* y0 = (float*)(ws + off);     off = align16(off + (size_t)N * OUT_C * 4);
    float* y1 = (float*)(ws + off);     off = align16(off + (size_t)N * OUT_C * 4);

    const int B = 256;
    const int nb_n = (N + B - 1) / B;
    const int nb_e = (E + B - 1) / B;

    // ---- CSR build ----
    zero_int_kernel<<<nb_n, B, 0, stream>>>(cnt, N);
    count_kernel<<<nb_e, B, 0, stream>>>(col, cnt, E);
    dinv_kernel<<<nb_n, B, 0, stream>>>(cnt, dinv, N);
    scan_pass1_kernel<<<nb_n, B, 0, stream>>>(cnt, partials, N);
    scan_pass2_kernel<<<1, 512, 0, stream>>>(partials, row_start, nb_n, N);
    scan_pass3_kernel<<<nb_n, B, 0, stream>>>(cnt, partials, row_start, cursor, N);
    csr_fill_kernel<<<nb_e, B, 0, stream>>>(row, col, dinv, cursor, csr, E);

    // ---- linear first (propagation commutes with W): y0 = x @ W^T ----
    linear_kernel<<<(N + NPB - 1) / NPB, B, 0, stream>>>(x, W, y0, N);

    // ---- hop 1 ----
    gather_kernel<false><<<(N + 3) / 4, B, 0, stream>>>(y0, y1, row_start, csr, dinv, b, N);

    // ---- hop 2 + bias + sigmoid ----
    gather_kernel<true><<<(N + 3) / 4, B, 0, stream>>>(y1, out, row_start, csr, dinv, b, N);
}

// Round 6
// 1373.917 us; speedup vs baseline: 1.0019x; 1.0019x over previous
//
#include <hip/hip_runtime.h>
#include <hip/hip_bf16.h>
#include <math.h>

#define N_NODES 100000
#define N_EDGES 800000
#define IN_C 96
#define OUT_C 64
#define NPB 64   // nodes per block in linear kernel

// ================= CSR build =================

__global__ void zero_int_kernel(int* __restrict__ p, int n) {
    int i = blockIdx.x * blockDim.x + threadIdx.x;
    if (i < n) p[i] = 0;
}

__global__ void count_kernel(const int* __restrict__ col, int* __restrict__ cnt, int e) {
    int i = blockIdx.x * blockDim.x + threadIdx.x;
    if (i < e) atomicAdd(&cnt[col[i]], 1);
}

__global__ void dinv_kernel(const int* __restrict__ cnt, float* __restrict__ dinv, int n) {
    int i = blockIdx.x * blockDim.x + threadIdx.x;
    if (i < n) dinv[i] = rsqrtf((float)cnt[i] + 1.0f);
}

__global__ void scan_pass1_kernel(const int* __restrict__ cnt, int* __restrict__ partials, int n) {
    __shared__ int s[256];
    int i = blockIdx.x * 256 + threadIdx.x;
    int v = (i < n) ? cnt[i] : 0;
    s[threadIdx.x] = v;
    __syncthreads();
    for (int off = 128; off > 0; off >>= 1) {
        if (threadIdx.x < off) s[threadIdx.x] += s[threadIdx.x + off];
        __syncthreads();
    }
    if (threadIdx.x == 0) partials[blockIdx.x] = s[0];
}

__global__ void scan_pass2_kernel(int* __restrict__ partials, int* __restrict__ row_start,
                                  int nparts, int n_nodes) {
    __shared__ int s[512];
    int t = threadIdx.x;
    int v = (t < nparts) ? partials[t] : 0;
    s[t] = v;
    __syncthreads();
    for (int off = 1; off < 512; off <<= 1) {
        int tmp = (t >= off) ? s[t - off] : 0;
        __syncthreads();
        s[t] += tmp;
        __syncthreads();
    }
    if (t < nparts) partials[t] = s[t] - v;
    if (t == 511) row_start[n_nodes] = s[511];
}

__global__ void scan_pass3_kernel(const int* __restrict__ cnt, const int* __restrict__ partials,
                                  int* __restrict__ row_start, int* __restrict__ cursor, int n) {
    __shared__ int s[256];
    int i = blockIdx.x * 256 + threadIdx.x;
    int t = threadIdx.x;
    int v = (i < n) ? cnt[i] : 0;
    s[t] = v;
    __syncthreads();
    for (int off = 1; off < 256; off <<= 1) {
        int tmp = (t >= off) ? s[t - off] : 0;
        __syncthreads();
        s[t] += tmp;
        __syncthreads();
    }
    if (i < n) {
        int start = partials[blockIdx.x] + s[t] - v;
        row_start[i] = start;
        cursor[i] = start;
    }
}

__global__ void csr_fill_kernel(const int* __restrict__ row, const int* __restrict__ col,
                                const float* __restrict__ dinv, int* __restrict__ cursor,
                                int2* __restrict__ csr, int e) {
    int i = blockIdx.x * blockDim.x + threadIdx.x;
    if (i >= e) return;
    int r = row[i];
    int c = col[i];
    float w = dinv[r] * dinv[c];
    int pos = atomicAdd(&cursor[c], 1);
    csr[pos] = make_int2(r, __float_as_int(w));
}

// ================= linear: y0 = x @ W^T (no bias) =================
// lane = output channel. W chunked 16 ch at a time (16 VGPRs live),
// 16 node-accumulators per thread. __launch_bounds__(256,4): VGPR cap 128
// (default no-bounds cap of 64 forced scratch spill in R3/R4 -> GBs of
// FETCH/WRITE traffic). Working set ~60-70 VGPR fits under 128; keeps
// 4 waves/SIMD for latency hiding.

__global__ __launch_bounds__(256, 4) void linear_kernel(
        const float* __restrict__ x, const float* __restrict__ W,
        float* __restrict__ y, int n) {
    __shared__ float xs[NPB * IN_C];   // 24 KB

    int lane = threadIdx.x & 63;
    int wv = threadIdx.x >> 6;         // wave 0..3; wave handles 16 nodes

    int node0 = blockIdx.x * NPB;

    // cooperative coalesced stage of x: 1536 float4, stride-1 LDS writes
    const float4* xg = (const float4*)(x + (size_t)node0 * IN_C);
    float4* xs4 = (float4*)xs;
    int avail4 = (n - node0) * (IN_C / 4);
    if (avail4 > NPB * (IN_C / 4)) avail4 = NPB * (IN_C / 4);
    for (int i = threadIdx.x; i < NPB * (IN_C / 4); i += 256) {
        xs4[i] = (i < avail4) ? xg[i] : make_float4(0.f, 0.f, 0.f, 0.f);
    }
    __syncthreads();

    const float4* Wrow = (const float4*)(W + (size_t)lane * IN_C);  // 24 float4, L1-resident

    float acc[16];
#pragma unroll
    for (int k = 0; k < 16; ++k) acc[k] = 0.0f;

#pragma unroll
    for (int cc = 0; cc < 6; ++cc) {               // 6 chunks x 16 channels
        float4 w0 = Wrow[cc * 4 + 0];
        float4 w1 = Wrow[cc * 4 + 1];
        float4 w2 = Wrow[cc * 4 + 2];
        float4 w3 = Wrow[cc * 4 + 3];
#pragma unroll
        for (int k = 0; k < 16; ++k) {
            const float4* xr = xs4 + (wv * 16 + k) * (IN_C / 4) + cc * 4;
            float4 x0 = xr[0], x1 = xr[1], x2 = xr[2], x3 = xr[3];
            float a = acc[k];
            a += x0.x * w0.x + x0.y * w0.y + x0.z * w0.z + x0.w * w0.w;
            a += x1.x * w1.x + x1.y * w1.y + x1.z * w1.z + x1.w * w1.w;
            a += x2.x * w2.x + x2.y * w2.y + x2.z * w2.z + x2.w * w2.w;
            a += x3.x * w3.x + x3.y * w3.y + x3.z * w3.z + x3.w * w3.w;
            acc[k] = a;
        }
    }

#pragma unroll
    for (int k = 0; k < 16; ++k) {
        int node = node0 + wv * 16 + k;
        if (node < n) y[(size_t)node * OUT_C + lane] = acc[k];
    }
}

// ================= gather hop: one wave per node, lane = channel =================

template <bool FINAL>
__global__ void gather_kernel(const float* __restrict__ src, float* __restrict__ dst,
                              const int* __restrict__ row_start, const int2* __restrict__ csr,
                              const float* __restrict__ dinv, const float* __restrict__ bias,
                              int n) {
    int node = blockIdx.x * (blockDim.x >> 6) + (threadIdx.x >> 6);
    if (node >= n) return;
    int ch = threadIdx.x & 63;

    float s = dinv[node];
    float acc0 = s * s * src[(size_t)node * OUT_C + ch];
    float acc1 = 0.0f;

    int beg = row_start[node];
    int end = row_start[node + 1];
    int j = beg;
    for (; j + 1 < end; j += 2) {
        int2 p0 = csr[j];
        int2 p1 = csr[j + 1];
        float v0 = src[(size_t)p0.x * OUT_C + ch];
        float v1 = src[(size_t)p1.x * OUT_C + ch];
        acc0 += __int_as_float(p0.y) * v0;
        acc1 += __int_as_float(p1.y) * v1;
    }
    if (j < end) {
        int2 p = csr[j];
        acc0 += __int_as_float(p.y) * src[(size_t)p.x * OUT_C + ch];
    }
    float acc = acc0 + acc1;
    if (FINAL) {
        acc += bias[ch];
        acc = 1.0f / (1.0f + __expf(-acc));
    }
    dst[(size_t)node * OUT_C + ch] = acc;
}

// ================= launch =================

static inline size_t align16(size_t x) { return (x + 15) & ~(size_t)15; }

extern "C" void kernel_launch(void* const* d_in, const int* in_sizes, int n_in,
                              void* d_out, int out_size, void* d_ws, size_t ws_size,
                              hipStream_t stream) {
    const float* x = (const float*)d_in[0];
    const int* edge_index = (const int*)d_in[1];
    const float* W = (const float*)d_in[2];
    const float* b = (const float*)d_in[3];
    float* out = (float*)d_out;

    const int N = N_NODES;
    const int E = in_sizes[1] / 2;

    const int* row = edge_index;        // source
    const int* col = edge_index + E;    // destination

    char* ws = (char*)d_ws;
    size_t off = 0;
    int* cnt = (int*)(ws + off);        off = align16(off + (size_t)N * 4);
    float* dinv = (float*)(ws + off);   off = align16(off + (size_t)N * 4);
    int* row_start = (int*)(ws + off);  off = align16(off + (size_t)(N + 1) * 4);
    int* cursor = (int*)(ws + off);     off = align16(off + (size_t)N * 4);
    int* partials = (int*)(ws + off);   off = align16(off + 512 * 4);
    int2* csr = (int2*)(ws + off);      off = align16(off + (size_t)E * 8);
    float* y0 = (float*)(ws + off);     off = align16(off + (size_t)N * OUT_C * 4);
    float* y1 = (float*)(ws + off);     off = align16(off + (size_t)N * OUT_C * 4);

    const int B = 256;
    const int nb_n = (N + B - 1) / B;
    const int nb_e = (E + B - 1) / B;

    // ---- CSR build ----
    zero_int_kernel<<<nb_n, B, 0, stream>>>(cnt, N);
    count_kernel<<<nb_e, B, 0, stream>>>(col, cnt, E);
    dinv_kernel<<<nb_n, B, 0, stream>>>(cnt, dinv, N);
    scan_pass1_kernel<<<nb_n, B, 0, stream>>>(cnt, partials, N);
    scan_pass2_kernel<<<1, 512, 0, stream>>>(partials, row_start, nb_n, N);
    scan_pass3_kernel<<<nb_n, B, 0, stream>>>(cnt, partials, row_start, cursor, N);
    csr_fill_kernel<<<nb_e, B, 0, stream>>>(row, col, dinv, cursor, csr, E);

    // ---- linear first (propagation commutes with W): y0 = x @ W^T ----
    linear_kernel<<<(N + NPB - 1) / NPB, B, 0, stream>>>(x, W, y0, N);

    // ---- hop 1 ----
    gather_kernel<false><<<(N + 3) / 4, B, 0, stream>>>(y0, y1, row_start, csr, dinv, b, N);

    // ---- hop 2 + bias + sigmoid ----
    gather_kernel<true><<<(N + 3) / 4, B, 0, stream>>>(y1, out, row_start, csr, dinv, b, N);
}

// Round 7
// 333.406 us; speedup vs baseline: 4.1288x; 4.1209x over previous
//
#include <hip/hip_runtime.h>
#include <hip/hip_bf16.h>
#include <math.h>

#define N_NODES 100000
#define N_EDGES 800000
#define IN_C 96
#define OUT_C 64
#define NPB 64   // nodes per block in linear kernel
#define C4 (IN_C / 4)   // 24 float4 chunks per node

// ================= CSR build =================

__global__ void zero_int_kernel(int* __restrict__ p, int n) {
    int i = blockIdx.x * blockDim.x + threadIdx.x;
    if (i < n) p[i] = 0;
}

__global__ void count_kernel(const int* __restrict__ col, int* __restrict__ cnt, int e) {
    int i = blockIdx.x * blockDim.x + threadIdx.x;
    if (i < e) atomicAdd(&cnt[col[i]], 1);
}

__global__ void dinv_kernel(const int* __restrict__ cnt, float* __restrict__ dinv, int n) {
    int i = blockIdx.x * blockDim.x + threadIdx.x;
    if (i < n) dinv[i] = rsqrtf((float)cnt[i] + 1.0f);
}

__global__ void scan_pass1_kernel(const int* __restrict__ cnt, int* __restrict__ partials, int n) {
    __shared__ int s[256];
    int i = blockIdx.x * 256 + threadIdx.x;
    int v = (i < n) ? cnt[i] : 0;
    s[threadIdx.x] = v;
    __syncthreads();
    for (int off = 128; off > 0; off >>= 1) {
        if (threadIdx.x < off) s[threadIdx.x] += s[threadIdx.x + off];
        __syncthreads();
    }
    if (threadIdx.x == 0) partials[blockIdx.x] = s[0];
}

__global__ void scan_pass2_kernel(int* __restrict__ partials, int* __restrict__ row_start,
                                  int nparts, int n_nodes) {
    __shared__ int s[512];
    int t = threadIdx.x;
    int v = (t < nparts) ? partials[t] : 0;
    s[t] = v;
    __syncthreads();
    for (int off = 1; off < 512; off <<= 1) {
        int tmp = (t >= off) ? s[t - off] : 0;
        __syncthreads();
        s[t] += tmp;
        __syncthreads();
    }
    if (t < nparts) partials[t] = s[t] - v;
    if (t == 511) row_start[n_nodes] = s[511];
}

__global__ void scan_pass3_kernel(const int* __restrict__ cnt, const int* __restrict__ partials,
                                  int* __restrict__ row_start, int* __restrict__ cursor, int n) {
    __shared__ int s[256];
    int i = blockIdx.x * 256 + threadIdx.x;
    int t = threadIdx.x;
    int v = (i < n) ? cnt[i] : 0;
    s[t] = v;
    __syncthreads();
    for (int off = 1; off < 256; off <<= 1) {
        int tmp = (t >= off) ? s[t - off] : 0;
        __syncthreads();
        s[t] += tmp;
        __syncthreads();
    }
    if (i < n) {
        int start = partials[blockIdx.x] + s[t] - v;
        row_start[i] = start;
        cursor[i] = start;
    }
}

__global__ void csr_fill_kernel(const int* __restrict__ row, const int* __restrict__ col,
                                const float* __restrict__ dinv, int* __restrict__ cursor,
                                int2* __restrict__ csr, int e) {
    int i = blockIdx.x * blockDim.x + threadIdx.x;
    if (i >= e) return;
    int r = row[i];
    int c = col[i];
    float w = dinv[r] * dinv[c];
    int pos = atomicAdd(&cursor[c], 1);
    csr[pos] = make_int2(r, __float_as_int(w));
}

// ================= linear: y0 = x @ W^T (no bias) =================
// Array-free design: R3-R6's register-array versions (acc[16]/wreg[]) made
// the scheduler hoist LDS-load chunks into long live ranges and spill them
// to scratch (2.26 GB WRITE_SIZE). Here: 4 scalar accumulators, tight
// unroll-1 inner loop (5 LDS loads + 16 FMA), live set ~30 VGPRs.
// wt4[c4*64+o] read at lane-stride 16B = conflict-free; xs reads broadcast.

__global__ void linear_kernel(const float* __restrict__ x, const float* __restrict__ W,
                              float* __restrict__ y, int n) {
    __shared__ float4 wt4[C4 * 64];    // wt4[c4*64+o] = W[o][4c4..4c4+3]  (24.5 KB)
    __shared__ float4 xs4[NPB * C4];   // xs4[nl*24+c4]                    (24.5 KB)

    int tid = threadIdx.x;
    int lane = tid & 63;
    int wv = tid >> 6;                 // wave 0..3; wave handles 16 nodes

    // stage W transposed (once per block, amortized over 64 nodes)
    for (int idx = tid; idx < C4 * 64; idx += 256) {
        int o = idx & 63;
        int c4 = idx >> 6;
        wt4[idx] = ((const float4*)(W + (size_t)o * IN_C))[c4];
    }

    // stage x coalesced
    int node0 = blockIdx.x * NPB;
    const float4* xg = (const float4*)(x + (size_t)node0 * IN_C);
    int avail4 = (n - node0) * C4;
    if (avail4 > NPB * C4) avail4 = NPB * C4;
    for (int i = tid; i < NPB * C4; i += 256) {
        xs4[i] = (i < avail4) ? xg[i] : make_float4(0.f, 0.f, 0.f, 0.f);
    }
    __syncthreads();

    // each wave: 16 nodes, in groups of 4 sharing each w4 read
    for (int g = 0; g < 4; ++g) {
        int nl = wv * 16 + g * 4;
        const float4* xp = xs4 + nl * C4;
        float a0 = 0.f, a1 = 0.f, a2 = 0.f, a3 = 0.f;
#pragma unroll 1
        for (int c4 = 0; c4 < C4; ++c4) {
            float4 w = wt4[c4 * 64 + lane];
            float4 xa = xp[c4];
            float4 xb = xp[C4 + c4];
            float4 xc = xp[2 * C4 + c4];
            float4 xd = xp[3 * C4 + c4];
            a0 += xa.x * w.x + xa.y * w.y + xa.z * w.z + xa.w * w.w;
            a1 += xb.x * w.x + xb.y * w.y + xb.z * w.z + xb.w * w.w;
            a2 += xc.x * w.x + xc.y * w.y + xc.z * w.z + xc.w * w.w;
            a3 += xd.x * w.x + xd.y * w.y + xd.z * w.z + xd.w * w.w;
        }
        int node = node0 + nl;
        if (node + 3 < n) {
            y[(size_t)node * OUT_C + lane] = a0;
            y[(size_t)(node + 1) * OUT_C + lane] = a1;
            y[(size_t)(node + 2) * OUT_C + lane] = a2;
            y[(size_t)(node + 3) * OUT_C + lane] = a3;
        } else {
            if (node < n)     y[(size_t)node * OUT_C + lane] = a0;
            if (node + 1 < n) y[(size_t)(node + 1) * OUT_C + lane] = a1;
            if (node + 2 < n) y[(size_t)(node + 2) * OUT_C + lane] = a2;
            if (node + 3 < n) y[(size_t)(node + 3) * OUT_C + lane] = a3;
        }
    }
}

// ================= gather hop: one wave per node, lane = channel =================

template <bool FINAL>
__global__ void gather_kernel(const float* __restrict__ src, float* __restrict__ dst,
                              const int* __restrict__ row_start, const int2* __restrict__ csr,
                              const float* __restrict__ dinv, const float* __restrict__ bias,
                              int n) {
    int node = blockIdx.x * (blockDim.x >> 6) + (threadIdx.x >> 6);
    if (node >= n) return;
    int ch = threadIdx.x & 63;

    float s = dinv[node];
    float acc0 = s * s * src[(size_t)node * OUT_C + ch];
    float acc1 = 0.0f;

    int beg = row_start[node];
    int end = row_start[node + 1];
    int j = beg;
    for (; j + 1 < end; j += 2) {
        int2 p0 = csr[j];
        int2 p1 = csr[j + 1];
        float v0 = src[(size_t)p0.x * OUT_C + ch];
        float v1 = src[(size_t)p1.x * OUT_C + ch];
        acc0 += __int_as_float(p0.y) * v0;
        acc1 += __int_as_float(p1.y) * v1;
    }
    if (j < end) {
        int2 p = csr[j];
        acc0 += __int_as_float(p.y) * src[(size_t)p.x * OUT_C + ch];
    }
    float acc = acc0 + acc1;
    if (FINAL) {
        acc += bias[ch];
        acc = 1.0f / (1.0f + __expf(-acc));
    }
    dst[(size_t)node * OUT_C + ch] = acc;
}

// ================= launch =================

static inline size_t align16(size_t x) { return (x + 15) & ~(size_t)15; }

extern "C" void kernel_launch(void* const* d_in, const int* in_sizes, int n_in,
                              void* d_out, int out_size, void* d_ws, size_t ws_size,
                              hipStream_t stream) {
    const float* x = (const float*)d_in[0];
    const int* edge_index = (const int*)d_in[1];
    const float* W = (const float*)d_in[2];
    const float* b = (const float*)d_in[3];
    float* out = (float*)d_out;

    const int N = N_NODES;
    const int E = in_sizes[1] / 2;

    const int* row = edge_index;        // source
    const int* col = edge_index + E;    // destination

    char* ws = (char*)d_ws;
    size_t off = 0;
    int* cnt = (int*)(ws + off);        off = align16(off + (size_t)N * 4);
    float* dinv = (float*)(ws + off);   off = align16(off + (size_t)N * 4);
    int* row_start = (int*)(ws + off);  off = align16(off + (size_t)(N + 1) * 4);
    int* cursor = (int*)(ws + off);     off = align16(off + (size_t)N * 4);
    int* partials = (int*)(ws + off);   off = align16(off + 512 * 4);
    int2* csr = (int2*)(ws + off);      off = align16(off + (size_t)E * 8);
    float* y0 = (float*)(ws + off);     off = align16(off + (size_t)N * OUT_C * 4);
    float* y1 = (float*)(ws + off);     off = align16(off + (size_t)N * OUT_C * 4);

    const int B = 256;
    const int nb_n = (N + B - 1) / B;
    const int nb_e = (E + B - 1) / B;

    // ---- CSR build ----
    zero_int_kernel<<<nb_n, B, 0, stream>>>(cnt, N);
    count_kernel<<<nb_e, B, 0, stream>>>(col, cnt, E);
    dinv_kernel<<<nb_n, B, 0, stream>>>(cnt, dinv, N);
    scan_pass1_kernel<<<nb_n, B, 0, stream>>>(cnt, partials, N);
    scan_pass2_kernel<<<1, 512, 0, stream>>>(partials, row_start, nb_n, N);
    scan_pass3_kernel<<<nb_n, B, 0, stream>>>(cnt, partials, row_start, cursor, N);
    csr_fill_kernel<<<nb_e, B, 0, stream>>>(row, col, dinv, cursor, csr, E);

    // ---- linear first (propagation commutes with W): y0 = x @ W^T ----
    linear_kernel<<<(N + NPB - 1) / NPB, B, 0, stream>>>(x, W, y0, N);

    // ---- hop 1 ----
    gather_kernel<false><<<(N + 3) / 4, B, 0, stream>>>(y0, y1, row_start, csr, dinv, b, N);

    // ---- hop 2 + bias + sigmoid ----
    gather_kernel<true><<<(N + 3) / 4, B, 0, stream>>>(y1, out, row_start, csr, dinv, b, N);
}

// Round 8
// 303.662 us; speedup vs baseline: 4.5333x; 1.0979x over previous
//
#include <hip/hip_runtime.h>
#include <hip/hip_bf16.h>
#include <math.h>

#define N_NODES 100000
#define N_EDGES 800000
#define IN_C 96
#define OUT_C 64
#define NPB 64          // nodes per block in linear kernel
#define C4 (IN_C / 4)   // 24 float4 chunks per node

// bf16 helpers (manual, deterministic RNE)
__device__ __forceinline__ float bf2f(unsigned short h) {
    return __uint_as_float(((unsigned)h) << 16);
}
__device__ __forceinline__ unsigned short f2bf(float f) {
    unsigned u = __float_as_uint(f);
    unsigned r = 0x7FFFu + ((u >> 16) & 1u);
    return (unsigned short)((u + r) >> 16);
}

// ================= CSR build =================

__global__ void zero_int_kernel(int* __restrict__ p, int n) {
    int i = blockIdx.x * blockDim.x + threadIdx.x;
    if (i < n) p[i] = 0;
}

__global__ void count_kernel(const int* __restrict__ col, int* __restrict__ cnt, int e) {
    int i = blockIdx.x * blockDim.x + threadIdx.x;
    if (i < e) atomicAdd(&cnt[col[i]], 1);
}

__global__ void scan_pass1_kernel(const int* __restrict__ cnt, int* __restrict__ partials, int n) {
    __shared__ int s[256];
    int i = blockIdx.x * 256 + threadIdx.x;
    int v = (i < n) ? cnt[i] : 0;
    s[threadIdx.x] = v;
    __syncthreads();
    for (int off = 128; off > 0; off >>= 1) {
        if (threadIdx.x < off) s[threadIdx.x] += s[threadIdx.x + off];
        __syncthreads();
    }
    if (threadIdx.x == 0) partials[blockIdx.x] = s[0];
}

__global__ void scan_pass2_kernel(int* __restrict__ partials, int* __restrict__ row_start,
                                  int nparts, int n_nodes) {
    __shared__ int s[512];
    int t = threadIdx.x;
    int v = (t < nparts) ? partials[t] : 0;
    s[t] = v;
    __syncthreads();
    for (int off = 1; off < 512; off <<= 1) {
        int tmp = (t >= off) ? s[t - off] : 0;
        __syncthreads();
        s[t] += tmp;
        __syncthreads();
    }
    if (t < nparts) partials[t] = s[t] - v;
    if (t == 511) row_start[n_nodes] = s[511];
}

// pass 3 also computes dinv (folds old dinv_kernel in)
__global__ void scan_pass3_kernel(const int* __restrict__ cnt, const int* __restrict__ partials,
                                  int* __restrict__ row_start, int* __restrict__ cursor,
                                  float* __restrict__ dinv, int n) {
    __shared__ int s[256];
    int i = blockIdx.x * 256 + threadIdx.x;
    int t = threadIdx.x;
    int v = (i < n) ? cnt[i] : 0;
    s[t] = v;
    __syncthreads();
    for (int off = 1; off < 256; off <<= 1) {
        int tmp = (t >= off) ? s[t - off] : 0;
        __syncthreads();
        s[t] += tmp;
        __syncthreads();
    }
    if (i < n) {
        int start = partials[blockIdx.x] + s[t] - v;
        row_start[i] = start;
        cursor[i] = start;
        dinv[i] = rsqrtf((float)v + 1.0f);
    }
}

__global__ void csr_fill_kernel(const int* __restrict__ row, const int* __restrict__ col,
                                const float* __restrict__ dinv, int* __restrict__ cursor,
                                int2* __restrict__ csr, int e) {
    int i = blockIdx.x * blockDim.x + threadIdx.x;
    if (i >= e) return;
    int r = row[i];
    int c = col[i];
    float w = dinv[r] * dinv[c];
    int pos = atomicAdd(&cursor[c], 1);
    csr[pos] = make_int2(r, __float_as_int(w));
}

// ================= linear: y0 = x @ W^T (bf16 out) =================
// Array-free (R7 win): 4 scalar accumulators, unroll-1 inner loop, ~30 VGPR
// live set; no register-array spill. wt4 lane-stride 16B conflict-free.

__global__ void linear_kernel(const float* __restrict__ x, const float* __restrict__ W,
                              unsigned short* __restrict__ y, int n) {
    __shared__ float4 wt4[C4 * 64];    // wt4[c4*64+o] = W[o][4c4..4c4+3]
    __shared__ float4 xs4[NPB * C4];

    int tid = threadIdx.x;
    int lane = tid & 63;
    int wv = tid >> 6;

    for (int idx = tid; idx < C4 * 64; idx += 256) {
        int o = idx & 63;
        int c4 = idx >> 6;
        wt4[idx] = ((const float4*)(W + (size_t)o * IN_C))[c4];
    }

    int node0 = blockIdx.x * NPB;
    const float4* xg = (const float4*)(x + (size_t)node0 * IN_C);
    int avail4 = (n - node0) * C4;
    if (avail4 > NPB * C4) avail4 = NPB * C4;
    for (int i = tid; i < NPB * C4; i += 256) {
        xs4[i] = (i < avail4) ? xg[i] : make_float4(0.f, 0.f, 0.f, 0.f);
    }
    __syncthreads();

    for (int g = 0; g < 4; ++g) {
        int nl = wv * 16 + g * 4;
        const float4* xp = xs4 + nl * C4;
        float a0 = 0.f, a1 = 0.f, a2 = 0.f, a3 = 0.f;
#pragma unroll 1
        for (int c4 = 0; c4 < C4; ++c4) {
            float4 w = wt4[c4 * 64 + lane];
            float4 xa = xp[c4];
            float4 xb = xp[C4 + c4];
            float4 xc = xp[2 * C4 + c4];
            float4 xd = xp[3 * C4 + c4];
            a0 += xa.x * w.x + xa.y * w.y + xa.z * w.z + xa.w * w.w;
            a1 += xb.x * w.x + xb.y * w.y + xb.z * w.z + xb.w * w.w;
            a2 += xc.x * w.x + xc.y * w.y + xc.z * w.z + xc.w * w.w;
            a3 += xd.x * w.x + xd.y * w.y + xd.z * w.z + xd.w * w.w;
        }
        int node = node0 + nl;
        if (node + 3 < n) {
            y[(size_t)node * OUT_C + lane] = f2bf(a0);
            y[(size_t)(node + 1) * OUT_C + lane] = f2bf(a1);
            y[(size_t)(node + 2) * OUT_C + lane] = f2bf(a2);
            y[(size_t)(node + 3) * OUT_C + lane] = f2bf(a3);
        } else {
            if (node < n)     y[(size_t)node * OUT_C + lane] = f2bf(a0);
            if (node + 1 < n) y[(size_t)(node + 1) * OUT_C + lane] = f2bf(a1);
            if (node + 2 < n) y[(size_t)(node + 2) * OUT_C + lane] = f2bf(a2);
            if (node + 3 < n) y[(size_t)(node + 3) * OUT_C + lane] = f2bf(a3);
        }
    }
}

// ================= gather hop: one wave per node, lane = channel =================
// src in bf16 (halves random-gather bytes: 128 B/edge). Unroll-4 edge loop
// for 4 outstanding gathers (latency-bound per R7 counters: 26% VALU, 33% HBM).

template <bool FINAL>
__global__ void gather_kernel(const unsigned short* __restrict__ src,
                              unsigned short* __restrict__ dst_bf,
                              float* __restrict__ dst_f32,
                              const int* __restrict__ row_start, const int2* __restrict__ csr,
                              const float* __restrict__ dinv, const float* __restrict__ bias,
                              int n) {
    int node = blockIdx.x * (blockDim.x >> 6) + (threadIdx.x >> 6);
    if (node >= n) return;
    int ch = threadIdx.x & 63;

    float s = dinv[node];
    float acc0 = s * s * bf2f(src[(size_t)node * OUT_C + ch]);
    float acc1 = 0.f, acc2 = 0.f, acc3 = 0.f;

    int beg = row_start[node];
    int end = row_start[node + 1];
    int j = beg;
    for (; j + 3 < end; j += 4) {
        int2 p0 = csr[j];
        int2 p1 = csr[j + 1];
        int2 p2 = csr[j + 2];
        int2 p3 = csr[j + 3];
        float v0 = bf2f(src[(size_t)p0.x * OUT_C + ch]);
        float v1 = bf2f(src[(size_t)p1.x * OUT_C + ch]);
        float v2 = bf2f(src[(size_t)p2.x * OUT_C + ch]);
        float v3 = bf2f(src[(size_t)p3.x * OUT_C + ch]);
        acc0 += __int_as_float(p0.y) * v0;
        acc1 += __int_as_float(p1.y) * v1;
        acc2 += __int_as_float(p2.y) * v2;
        acc3 += __int_as_float(p3.y) * v3;
    }
    for (; j < end; ++j) {
        int2 p = csr[j];
        acc0 += __int_as_float(p.y) * bf2f(src[(size_t)p.x * OUT_C + ch]);
    }
    float acc = (acc0 + acc1) + (acc2 + acc3);
    if (FINAL) {
        acc += bias[ch];
        acc = 1.0f / (1.0f + __expf(-acc));
        dst_f32[(size_t)node * OUT_C + ch] = acc;
    } else {
        dst_bf[(size_t)node * OUT_C + ch] = f2bf(acc);
    }
}

// ================= launch =================

static inline size_t align16(size_t x) { return (x + 15) & ~(size_t)15; }

extern "C" void kernel_launch(void* const* d_in, const int* in_sizes, int n_in,
                              void* d_out, int out_size, void* d_ws, size_t ws_size,
                              hipStream_t stream) {
    const float* x = (const float*)d_in[0];
    const int* edge_index = (const int*)d_in[1];
    const float* W = (const float*)d_in[2];
    const float* b = (const float*)d_in[3];
    float* out = (float*)d_out;

    const int N = N_NODES;
    const int E = in_sizes[1] / 2;

    const int* row = edge_index;        // source
    const int* col = edge_index + E;    // destination

    char* ws = (char*)d_ws;
    size_t off = 0;
    int* cnt = (int*)(ws + off);             off = align16(off + (size_t)N * 4);
    float* dinv = (float*)(ws + off);        off = align16(off + (size_t)N * 4);
    int* row_start = (int*)(ws + off);       off = align16(off + (size_t)(N + 1) * 4);
    int* cursor = (int*)(ws + off);          off = align16(off + (size_t)N * 4);
    int* partials = (int*)(ws + off);        off = align16(off + 512 * 4);
    int2* csr = (int2*)(ws + off);           off = align16(off + (size_t)E * 8);
    unsigned short* y0 = (unsigned short*)(ws + off); off = align16(off + (size_t)N * OUT_C * 2);
    unsigned short* y1 = (unsigned short*)(ws + off); off = align16(off + (size_t)N * OUT_C * 2);

    const int B = 256;
    const int nb_n = (N + B - 1) / B;
    const int nb_e = (E + B - 1) / B;

    // ---- CSR build ----
    zero_int_kernel<<<nb_n, B, 0, stream>>>(cnt, N);
    count_kernel<<<nb_e, B, 0, stream>>>(col, cnt, E);
    scan_pass1_kernel<<<nb_n, B, 0, stream>>>(cnt, partials, N);
    scan_pass2_kernel<<<1, 512, 0, stream>>>(partials, row_start, nb_n, N);
    scan_pass3_kernel<<<nb_n, B, 0, stream>>>(cnt, partials, row_start, cursor, dinv, N);
    csr_fill_kernel<<<nb_e, B, 0, stream>>>(row, col, dinv, cursor, csr, E);

    // ---- linear first (propagation commutes with W): y0 = x @ W^T (bf16) ----
    linear_kernel<<<(N + NPB - 1) / NPB, B, 0, stream>>>(x, W, y0, N);

    // ---- hop 1: y1 = D^-1/2 (A+I) D^-1/2 y0 ----
    gather_kernel<false><<<(N + 3) / 4, B, 0, stream>>>(y0, y1, nullptr, row_start, csr, dinv, b, N);

    // ---- hop 2 + bias + sigmoid -> out (f32) ----
    gather_kernel<true><<<(N + 3) / 4, B, 0, stream>>>(y1, nullptr, out, row_start, csr, dinv, b, N);
}

// Round 9
// 269.457 us; speedup vs baseline: 5.1087x; 1.1269x over previous
//
#include <hip/hip_runtime.h>
#include <hip/hip_bf16.h>
#include <math.h>

#define N_NODES 100000
#define N_EDGES 800000
#define IN_C 96
#define OUT_C 64
#define NPB 64          // nodes per block in linear kernel
#define C4 (IN_C / 4)   // 24 float4 chunks per node
#define XPAD 104        // padded LDS row stride in bf16 elems (208 B = 13 quad-banks, 2-way free)

typedef __attribute__((ext_vector_type(8))) short bf16x8;
typedef __attribute__((ext_vector_type(4))) float f32x4;

// bf16 helpers (manual, deterministic RNE)
__device__ __forceinline__ float bf2f(unsigned short h) {
    return __uint_as_float(((unsigned)h) << 16);
}
__device__ __forceinline__ unsigned short f2bf(float f) {
    unsigned u = __float_as_uint(f);
    unsigned r = 0x7FFFu + ((u >> 16) & 1u);
    return (unsigned short)((u + r) >> 16);
}
__device__ __forceinline__ unsigned pack2bf(float a, float b) {
    return (unsigned)f2bf(a) | ((unsigned)f2bf(b) << 16);
}

// ================= CSR build =================

__global__ void zero_int_kernel(int* __restrict__ p, int n) {
    int i = blockIdx.x * blockDim.x + threadIdx.x;
    if (i < n) p[i] = 0;
}

__global__ void count_kernel(const int* __restrict__ col, int* __restrict__ cnt, int e) {
    int i = blockIdx.x * blockDim.x + threadIdx.x;
    if (i < e) atomicAdd(&cnt[col[i]], 1);
}

__global__ void scan_pass1_kernel(const int* __restrict__ cnt, int* __restrict__ partials, int n) {
    __shared__ int s[256];
    int i = blockIdx.x * 256 + threadIdx.x;
    int v = (i < n) ? cnt[i] : 0;
    s[threadIdx.x] = v;
    __syncthreads();
    for (int off = 128; off > 0; off >>= 1) {
        if (threadIdx.x < off) s[threadIdx.x] += s[threadIdx.x + off];
        __syncthreads();
    }
    if (threadIdx.x == 0) partials[blockIdx.x] = s[0];
}

__global__ void scan_pass2_kernel(int* __restrict__ partials, int* __restrict__ row_start,
                                  int nparts, int n_nodes) {
    __shared__ int s[512];
    int t = threadIdx.x;
    int v = (t < nparts) ? partials[t] : 0;
    s[t] = v;
    __syncthreads();
    for (int off = 1; off < 512; off <<= 1) {
        int tmp = (t >= off) ? s[t - off] : 0;
        __syncthreads();
        s[t] += tmp;
        __syncthreads();
    }
    if (t < nparts) partials[t] = s[t] - v;
    if (t == 511) row_start[n_nodes] = s[511];
}

// pass 3 also computes dinv
__global__ void scan_pass3_kernel(const int* __restrict__ cnt, const int* __restrict__ partials,
                                  int* __restrict__ row_start, int* __restrict__ cursor,
                                  float* __restrict__ dinv, int n) {
    __shared__ int s[256];
    int i = blockIdx.x * 256 + threadIdx.x;
    int t = threadIdx.x;
    int v = (i < n) ? cnt[i] : 0;
    s[t] = v;
    __syncthreads();
    for (int off = 1; off < 256; off <<= 1) {
        int tmp = (t >= off) ? s[t - off] : 0;
        __syncthreads();
        s[t] += tmp;
        __syncthreads();
    }
    if (i < n) {
        int start = partials[blockIdx.x] + s[t] - v;
        row_start[i] = start;
        cursor[i] = start;
        dinv[i] = rsqrtf((float)v + 1.0f);
    }
}

__global__ void csr_fill_kernel(const int* __restrict__ row, const int* __restrict__ col,
                                const float* __restrict__ dinv, int* __restrict__ cursor,
                                int2* __restrict__ csr, int e) {
    int i = blockIdx.x * blockDim.x + threadIdx.x;
    if (i >= e) return;
    int r = row[i];
    int c = col[i];
    float w = dinv[r] * dinv[c];
    int pos = atomicAdd(&cursor[c], 1);
    csr[pos] = make_int2(r, __float_as_int(w));
}

// ================= linear (MFMA): y0 = bf16(x) @ bf16(W)^T =================
// R8's scalar-FMA version was LDS-throughput bound (5 b128 reads / 16 FMAs,
// ~58 us model = 52.8 us measured). MFMA 16x16x32_bf16 layouts (m89/m91
// verified): A: m=lane&15, k=(lane>>4)*8+j (8 contiguous bf16 -> b128);
// B: n=lane&15, same k; C/D: col(n)=lane&15, row(m)=(lane>>4)*4+reg.
// Block: 64 nodes; wave wv handles node tile wv*16..+15 x all 64 outputs
// (4 N-tiles x 3 K-chunks = 12 MFMAs).

__global__ void linear_kernel(const float* __restrict__ x, const float* __restrict__ W,
                              unsigned short* __restrict__ y, int n) {
    __shared__ unsigned short wbf[64 * XPAD];   // W[o][c] bf16, padded (13.3 KB)
    __shared__ unsigned short xbf[64 * XPAD];   // x[nl][c] bf16, padded (13.3 KB)

    int tid = threadIdx.x;
    int lane = tid & 63;
    int wv = tid >> 6;
    int node0 = blockIdx.x * 64;

    // stage W -> bf16 LDS (once per block, 64x96)
    for (int i = tid; i < 64 * C4; i += 256) {
        int o = i / C4;
        int c4 = i - o * C4;
        float4 v = ((const float4*)(W + (size_t)o * IN_C))[c4];
        uint2 pk;
        pk.x = pack2bf(v.x, v.y);
        pk.y = pack2bf(v.z, v.w);
        *(uint2*)&wbf[o * XPAD + c4 * 4] = pk;
    }
    // stage x -> bf16 LDS (zero-fill OOB)
    const float4* xg = (const float4*)(x + (size_t)node0 * IN_C);
    int avail4 = (n - node0) * C4;
    if (avail4 > 64 * C4) avail4 = 64 * C4;
    for (int i = tid; i < 64 * C4; i += 256) {
        int nl = i / C4;
        int c4 = i - nl * C4;
        float4 v = (i < avail4) ? xg[i] : make_float4(0.f, 0.f, 0.f, 0.f);
        uint2 pk;
        pk.x = pack2bf(v.x, v.y);
        pk.y = pack2bf(v.z, v.w);
        *(uint2*)&xbf[nl * XPAD + c4 * 4] = pk;
    }
    __syncthreads();

    int l16 = lane & 15;
    int quad = lane >> 4;

    f32x4 acc0 = {0.f, 0.f, 0.f, 0.f};
    f32x4 acc1 = {0.f, 0.f, 0.f, 0.f};
    f32x4 acc2 = {0.f, 0.f, 0.f, 0.f};
    f32x4 acc3 = {0.f, 0.f, 0.f, 0.f};

#pragma unroll
    for (int kc = 0; kc < 3; ++kc) {
        bf16x8 a = *(const bf16x8*)&xbf[(wv * 16 + l16) * XPAD + kc * 32 + quad * 8];
        bf16x8 b0 = *(const bf16x8*)&wbf[(0 * 16 + l16) * XPAD + kc * 32 + quad * 8];
        bf16x8 b1 = *(const bf16x8*)&wbf[(1 * 16 + l16) * XPAD + kc * 32 + quad * 8];
        bf16x8 b2 = *(const bf16x8*)&wbf[(2 * 16 + l16) * XPAD + kc * 32 + quad * 8];
        bf16x8 b3 = *(const bf16x8*)&wbf[(3 * 16 + l16) * XPAD + kc * 32 + quad * 8];
        acc0 = __builtin_amdgcn_mfma_f32_16x16x32_bf16(a, b0, acc0, 0, 0, 0);
        acc1 = __builtin_amdgcn_mfma_f32_16x16x32_bf16(a, b1, acc1, 0, 0, 0);
        acc2 = __builtin_amdgcn_mfma_f32_16x16x32_bf16(a, b2, acc2, 0, 0, 0);
        acc3 = __builtin_amdgcn_mfma_f32_16x16x32_bf16(a, b3, acc3, 0, 0, 0);
    }

    // store: node = node0 + wv*16 + quad*4 + r, ch = nt*16 + l16
#pragma unroll
    for (int r = 0; r < 4; ++r) {
        int node = node0 + wv * 16 + quad * 4 + r;
        if (node < n) {
            size_t base = (size_t)node * OUT_C + l16;
            y[base + 0]  = f2bf(acc0[r]);
            y[base + 16] = f2bf(acc1[r]);
            y[base + 32] = f2bf(acc2[r]);
            y[base + 48] = f2bf(acc3[r]);
        }
    }
}

// ================= gather hop: one wave per node, lane = channel =================
// bf16 src (128 B/edge gather). Unroll-8 with scalar accumulators: 8
// outstanding gathers per wave (R8 was latency-bound: VALU 33%, HBM 28%).

template <bool FINAL>
__global__ void gather_kernel(const unsigned short* __restrict__ src,
                              unsigned short* __restrict__ dst_bf,
                              float* __restrict__ dst_f32,
                              const int* __restrict__ row_start, const int2* __restrict__ csr,
                              const float* __restrict__ dinv, const float* __restrict__ bias,
                              int n) {
    int node = blockIdx.x * (blockDim.x >> 6) + (threadIdx.x >> 6);
    if (node >= n) return;
    int ch = threadIdx.x & 63;
    const unsigned short* sc = src + ch;

    float s = dinv[node];
    float a0 = s * s * bf2f(sc[(size_t)node * OUT_C]);
    float a1 = 0.f, a2 = 0.f, a3 = 0.f, a4 = 0.f, a5 = 0.f, a6 = 0.f, a7 = 0.f;

    int beg = row_start[node];
    int end = row_start[node + 1];
    int j = beg;
    for (; j + 7 < end; j += 8) {
        int2 p0 = csr[j];
        int2 p1 = csr[j + 1];
        int2 p2 = csr[j + 2];
        int2 p3 = csr[j + 3];
        int2 p4 = csr[j + 4];
        int2 p5 = csr[j + 5];
        int2 p6 = csr[j + 6];
        int2 p7 = csr[j + 7];
        float v0 = bf2f(sc[(size_t)p0.x * OUT_C]);
        float v1 = bf2f(sc[(size_t)p1.x * OUT_C]);
        float v2 = bf2f(sc[(size_t)p2.x * OUT_C]);
        float v3 = bf2f(sc[(size_t)p3.x * OUT_C]);
        float v4 = bf2f(sc[(size_t)p4.x * OUT_C]);
        float v5 = bf2f(sc[(size_t)p5.x * OUT_C]);
        float v6 = bf2f(sc[(size_t)p6.x * OUT_C]);
        float v7 = bf2f(sc[(size_t)p7.x * OUT_C]);
        a0 += __int_as_float(p0.y) * v0;
        a1 += __int_as_float(p1.y) * v1;
        a2 += __int_as_float(p2.y) * v2;
        a3 += __int_as_float(p3.y) * v3;
        a4 += __int_as_float(p4.y) * v4;
        a5 += __int_as_float(p5.y) * v5;
        a6 += __int_as_float(p6.y) * v6;
        a7 += __int_as_float(p7.y) * v7;
    }
    for (; j + 3 < end; j += 4) {
        int2 p0 = csr[j];
        int2 p1 = csr[j + 1];
        int2 p2 = csr[j + 2];
        int2 p3 = csr[j + 3];
        float v0 = bf2f(sc[(size_t)p0.x * OUT_C]);
        float v1 = bf2f(sc[(size_t)p1.x * OUT_C]);
        float v2 = bf2f(sc[(size_t)p2.x * OUT_C]);
        float v3 = bf2f(sc[(size_t)p3.x * OUT_C]);
        a0 += __int_as_float(p0.y) * v0;
        a1 += __int_as_float(p1.y) * v1;
        a2 += __int_as_float(p2.y) * v2;
        a3 += __int_as_float(p3.y) * v3;
    }
    for (; j < end; ++j) {
        int2 p = csr[j];
        a0 += __int_as_float(p.y) * bf2f(sc[(size_t)p.x * OUT_C]);
    }
    float acc = ((a0 + a1) + (a2 + a3)) + ((a4 + a5) + (a6 + a7));
    if (FINAL) {
        acc += bias[ch];
        acc = 1.0f / (1.0f + __expf(-acc));
        dst_f32[(size_t)node * OUT_C + ch] = acc;
    } else {
        dst_bf[(size_t)node * OUT_C + ch] = f2bf(acc);
    }
}

// ================= launch =================

static inline size_t align16(size_t x) { return (x + 15) & ~(size_t)15; }

extern "C" void kernel_launch(void* const* d_in, const int* in_sizes, int n_in,
                              void* d_out, int out_size, void* d_ws, size_t ws_size,
                              hipStream_t stream) {
    const float* x = (const float*)d_in[0];
    const int* edge_index = (const int*)d_in[1];
    const float* W = (const float*)d_in[2];
    const float* b = (const float*)d_in[3];
    float* out = (float*)d_out;

    const int N = N_NODES;
    const int E = in_sizes[1] / 2;

    const int* row = edge_index;        // source
    const int* col = edge_index + E;    // destination

    char* ws = (char*)d_ws;
    size_t off = 0;
    int* cnt = (int*)(ws + off);             off = align16(off + (size_t)N * 4);
    float* dinv = (float*)(ws + off);        off = align16(off + (size_t)N * 4);
    int* row_start = (int*)(ws + off);       off = align16(off + (size_t)(N + 1) * 4);
    int* cursor = (int*)(ws + off);          off = align16(off + (size_t)N * 4);
    int* partials = (int*)(ws + off);        off = align16(off + 512 * 4);
    int2* csr = (int2*)(ws + off);           off = align16(off + (size_t)E * 8);
    unsigned short* y0 = (unsigned short*)(ws + off); off = align16(off + (size_t)N * OUT_C * 2);
    unsigned short* y1 = (unsigned short*)(ws + off); off = align16(off + (size_t)N * OUT_C * 2);

    const int B = 256;
    const int nb_n = (N + B - 1) / B;
    const int nb_e = (E + B - 1) / B;

    // ---- CSR build ----
    zero_int_kernel<<<nb_n, B, 0, stream>>>(cnt, N);
    count_kernel<<<nb_e, B, 0, stream>>>(col, cnt, E);
    scan_pass1_kernel<<<nb_n, B, 0, stream>>>(cnt, partials, N);
    scan_pass2_kernel<<<1, 512, 0, stream>>>(partials, row_start, nb_n, N);
    scan_pass3_kernel<<<nb_n, B, 0, stream>>>(cnt, partials, row_start, cursor, dinv, N);
    csr_fill_kernel<<<nb_e, B, 0, stream>>>(row, col, dinv, cursor, csr, E);

    // ---- linear first (propagation commutes with W): y0 = x @ W^T (bf16, MFMA) ----
    linear_kernel<<<(N + NPB - 1) / NPB, B, 0, stream>>>(x, W, y0, N);

    // ---- hop 1: y1 = D^-1/2 (A+I) D^-1/2 y0 ----
    gather_kernel<false><<<(N + 3) / 4, B, 0, stream>>>(y0, y1, nullptr, row_start, csr, dinv, b, N);

    // ---- hop 2 + bias + sigmoid -> out (f32) ----
    gather_kernel<true><<<(N + 3) / 4, B, 0, stream>>>(y1, nullptr, out, row_start, csr, dinv, b, N);
}

// Round 11
// 263.000 us; speedup vs baseline: 5.2341x; 1.0245x over previous
//
#include <hip/hip_runtime.h>
#include <hip/hip_bf16.h>
#include <math.h>

#define N_NODES 100000
#define N_EDGES 800000
#define IN_C 96
#define OUT_C 64
#define C4 (IN_C / 4)   // 24 float4 chunks per node
#define XPAD 104        // padded LDS row stride in bf16 elems
#define SCAN_B 512      // scan block width

typedef __attribute__((ext_vector_type(8))) short bf16x8;
typedef __attribute__((ext_vector_type(4))) float f32x4;

// bf16 helpers (manual, deterministic RNE)
__device__ __forceinline__ float bf2f(unsigned short h) {
    return __uint_as_float(((unsigned)h) << 16);
}
__device__ __forceinline__ unsigned short f2bf(float f) {
    unsigned u = __float_as_uint(f);
    unsigned r = 0x7FFFu + ((u >> 16) & 1u);
    return (unsigned short)((u + r) >> 16);
}
__device__ __forceinline__ unsigned pack2bf(float a, float b) {
    return (unsigned)f2bf(a) | ((unsigned)f2bf(b) << 16);
}
// packed csr entry: [src:17][w_bf15:15]  (w in (0,1] so bf16 sign bit is 0)
__device__ __forceinline__ float dec_w(unsigned p) {
    return __uint_as_float((p & 0x7FFFu) << 16);
}
__device__ __forceinline__ float lo_bf(unsigned v) { return __uint_as_float(v << 16); }
__device__ __forceinline__ float hi_bf(unsigned v) { return __uint_as_float(v & 0xFFFF0000u); }

// ================= CSR build =================

__global__ void zero_int_kernel(int* __restrict__ p, int n) {
    int i = blockIdx.x * blockDim.x + threadIdx.x;
    if (i < n) p[i] = 0;
}

__global__ void count_kernel(const int* __restrict__ col, int* __restrict__ cnt, int e) {
    int i = blockIdx.x * blockDim.x + threadIdx.x;
    if (i < e) atomicAdd(&cnt[col[i]], 1);
}

// per-512-block sums
__global__ void scan_pass1_kernel(const int* __restrict__ cnt, int* __restrict__ partials, int n) {
    __shared__ int s[SCAN_B];
    int i = blockIdx.x * SCAN_B + threadIdx.x;
    int v = (i < n) ? cnt[i] : 0;
    s[threadIdx.x] = v;
    __syncthreads();
    for (int off = SCAN_B / 2; off > 0; off >>= 1) {
        if (threadIdx.x < off) s[threadIdx.x] += s[threadIdx.x + off];
        __syncthreads();
    }
    if (threadIdx.x == 0) partials[blockIdx.x] = s[0];
}

// fused scan2+scan3: every block redundantly scans the partials (nparts<=512),
// then scans its own 512 cnt elements; writes row_start/cursor/dinv (+total).
__global__ void scan23_kernel(const int* __restrict__ cnt, const int* __restrict__ partials,
                              int* __restrict__ row_start, int* __restrict__ cursor,
                              float* __restrict__ dinv, int n, int nparts) {
    __shared__ int ps[SCAN_B];
    __shared__ int es[SCAN_B];
    int t = threadIdx.x;

    // inclusive scan of partials
    int pv = (t < nparts) ? partials[t] : 0;
    ps[t] = pv;
    __syncthreads();
    int run = pv;
    for (int off = 1; off < SCAN_B; off <<= 1) {
        int tmp = (t >= off) ? ps[t - off] : 0;
        __syncthreads();
        run += tmp;
        ps[t] = run;
        __syncthreads();
    }
    int total = ps[nparts - 1];
    __syncthreads();
    ps[t] = run - pv;   // exclusive
    __syncthreads();
    int block_off = ps[blockIdx.x];

    // inclusive scan of this block's cnt elements
    int i = blockIdx.x * SCAN_B + t;
    int v = (i < n) ? cnt[i] : 0;
    es[t] = v;
    __syncthreads();
    int erun = v;
    for (int off = 1; off < SCAN_B; off <<= 1) {
        int tmp = (t >= off) ? es[t - off] : 0;
        __syncthreads();
        erun += tmp;
        es[t] = erun;
        __syncthreads();
    }
    if (i < n) {
        int start = block_off + erun - v;   // exclusive
        row_start[i] = start;
        cursor[i] = start;
        dinv[i] = rsqrtf((float)v + 1.0f);
    }
    if (blockIdx.x == 0 && t == 0) row_start[n] = total;
}

// ================= fused: csr_fill (blocks < nb_fill) + linear (rest) =================
// fill: packed 4B csr entries (halves the cross-XCD partial-line writeback
// inflation seen in R9: 53.9 MB WRITE for 6.4 MB payload).
// linear: R9's MFMA kernel (m89/m91-verified 16x16x32_bf16 layouts), block
// range offset by nb_fill. Independent work, different bottlenecks -> overlap.

__global__ void fill_linear_kernel(const int* __restrict__ row, const int* __restrict__ col,
                                   const float* __restrict__ dinv, int* __restrict__ cursor,
                                   unsigned* __restrict__ csr, int e, int nb_fill,
                                   const float* __restrict__ x, const float* __restrict__ W,
                                   unsigned short* __restrict__ y, int n) {
    __shared__ unsigned short wbf[64 * XPAD];
    __shared__ unsigned short xbf[64 * XPAD];

    if ((int)blockIdx.x < nb_fill) {
        int i = blockIdx.x * 256 + threadIdx.x;
        if (i < e) {
            int r = row[i];
            int c = col[i];
            float w = dinv[r] * dinv[c];
            int pos = atomicAdd(&cursor[c], 1);
            csr[pos] = ((unsigned)r << 15) | (unsigned)f2bf(w);
        }
        return;
    }

    int bid = blockIdx.x - nb_fill;
    int tid = threadIdx.x;
    int lane = tid & 63;
    int wv = tid >> 6;
    int node0 = bid * 64;

    for (int i = tid; i < 64 * C4; i += 256) {
        int o = i / C4;
        int c4 = i - o * C4;
        float4 v = ((const float4*)(W + (size_t)o * IN_C))[c4];
        uint2 pk;
        pk.x = pack2bf(v.x, v.y);
        pk.y = pack2bf(v.z, v.w);
        *(uint2*)&wbf[o * XPAD + c4 * 4] = pk;
    }
    const float4* xg = (const float4*)(x + (size_t)node0 * IN_C);
    int avail4 = (n - node0) * C4;
    if (avail4 > 64 * C4) avail4 = 64 * C4;
    for (int i = tid; i < 64 * C4; i += 256) {
        int nl = i / C4;
        int c4 = i - nl * C4;
        float4 v = (i < avail4) ? xg[i] : make_float4(0.f, 0.f, 0.f, 0.f);
        uint2 pk;
        pk.x = pack2bf(v.x, v.y);
        pk.y = pack2bf(v.z, v.w);
        *(uint2*)&xbf[nl * XPAD + c4 * 4] = pk;
    }
    __syncthreads();

    int l16 = lane & 15;
    int quad = lane >> 4;

    f32x4 acc0 = {0.f, 0.f, 0.f, 0.f};
    f32x4 acc1 = {0.f, 0.f, 0.f, 0.f};
    f32x4 acc2 = {0.f, 0.f, 0.f, 0.f};
    f32x4 acc3 = {0.f, 0.f, 0.f, 0.f};

#pragma unroll
    for (int kc = 0; kc < 3; ++kc) {
        bf16x8 a = *(const bf16x8*)&xbf[(wv * 16 + l16) * XPAD + kc * 32 + quad * 8];
        bf16x8 b0 = *(const bf16x8*)&wbf[(0 * 16 + l16) * XPAD + kc * 32 + quad * 8];
        bf16x8 b1 = *(const bf16x8*)&wbf[(1 * 16 + l16) * XPAD + kc * 32 + quad * 8];
        bf16x8 b2 = *(const bf16x8*)&wbf[(2 * 16 + l16) * XPAD + kc * 32 + quad * 8];
        bf16x8 b3 = *(const bf16x8*)&wbf[(3 * 16 + l16) * XPAD + kc * 32 + quad * 8];
        acc0 = __builtin_amdgcn_mfma_f32_16x16x32_bf16(a, b0, acc0, 0, 0, 0);
        acc1 = __builtin_amdgcn_mfma_f32_16x16x32_bf16(a, b1, acc1, 0, 0, 0);
        acc2 = __builtin_amdgcn_mfma_f32_16x16x32_bf16(a, b2, acc2, 0, 0, 0);
        acc3 = __builtin_amdgcn_mfma_f32_16x16x32_bf16(a, b3, acc3, 0, 0, 0);
    }

#pragma unroll
    for (int r = 0; r < 4; ++r) {
        int node = node0 + wv * 16 + quad * 4 + r;
        if (node < n) {
            size_t base = (size_t)node * OUT_C + l16;
            y[base + 0]  = f2bf(acc0[r]);
            y[base + 16] = f2bf(acc1[r]);
            y[base + 32] = f2bf(acc2[r]);
            y[base + 48] = f2bf(acc3[r]);
        }
    }
}

// ================= gather hop: one wave per node, half-wave = edge parity =================
// 64 bf16 ch = 32 dwords; lane&31 = channel pair, lane>>5 = edge parity.
// 2 edges per load instruction, 8 edges in flight (unroll 4 per half);
// halves combined with __shfl_xor(.,32).

template <bool FINAL>
__global__ void gather_kernel(const unsigned short* __restrict__ src,
                              unsigned short* __restrict__ dst_bf,
                              float* __restrict__ dst_f32,
                              const int* __restrict__ row_start, const unsigned* __restrict__ csr,
                              const float* __restrict__ dinv, const float* __restrict__ bias,
                              int n) {
    int node = blockIdx.x * (blockDim.x >> 6) + (threadIdx.x >> 6);
    if (node >= n) return;
    int lane = threadIdx.x & 63;
    int half = lane >> 5;
    int c = lane & 31;                       // channels 2c, 2c+1
    const unsigned* srcp = (const unsigned*)src;

    float e0a = 0.f, e0b = 0.f, e1a = 0.f, e1b = 0.f;
    float e2a = 0.f, e2b = 0.f, e3a = 0.f, e3b = 0.f;

    // self-loop (half 0 only)
    unsigned pv = srcp[(size_t)node * 32 + c];
    float s = dinv[node];
    float ss = s * s;
    if (half == 0) { e0a = ss * lo_bf(pv); e0b = ss * hi_bf(pv); }

    int beg = row_start[node];
    int end = row_start[node + 1];
    int j = beg + half;
    for (; j + 6 < end; j += 8) {
        unsigned p0 = csr[j];
        unsigned p1 = csr[j + 2];
        unsigned p2 = csr[j + 4];
        unsigned p3 = csr[j + 6];
        unsigned v0 = srcp[(size_t)(p0 >> 15) * 32 + c];
        unsigned v1 = srcp[(size_t)(p1 >> 15) * 32 + c];
        unsigned v2 = srcp[(size_t)(p2 >> 15) * 32 + c];
        unsigned v3 = srcp[(size_t)(p3 >> 15) * 32 + c];
        float w0 = dec_w(p0), w1 = dec_w(p1), w2 = dec_w(p2), w3 = dec_w(p3);
        e0a += w0 * lo_bf(v0); e0b += w0 * hi_bf(v0);
        e1a += w1 * lo_bf(v1); e1b += w1 * hi_bf(v1);
        e2a += w2 * lo_bf(v2); e2b += w2 * hi_bf(v2);
        e3a += w3 * lo_bf(v3); e3b += w3 * hi_bf(v3);
    }
    for (; j < end; j += 2) {
        unsigned p = csr[j];
        unsigned v = srcp[(size_t)(p >> 15) * 32 + c];
        float w = dec_w(p);
        e0a += w * lo_bf(v); e0b += w * hi_bf(v);
    }
    float a0 = (e0a + e1a) + (e2a + e3a);
    float a1 = (e0b + e1b) + (e2b + e3b);
    a0 += __shfl_xor(a0, 32);
    a1 += __shfl_xor(a1, 32);

    if (FINAL) {
        float2 bb = ((const float2*)bias)[c];
        a0 = 1.0f / (1.0f + __expf(-(a0 + bb.x)));
        a1 = 1.0f / (1.0f + __expf(-(a1 + bb.y)));
        if (half == 0) ((float2*)dst_f32)[(size_t)node * 32 + c] = make_float2(a0, a1);
    } else {
        if (half == 0) ((unsigned*)dst_bf)[(size_t)node * 32 + c] = pack2bf(a0, a1);
    }
}

// ================= launch =================

static inline size_t align16(size_t x) { return (x + 15) & ~(size_t)15; }

extern "C" void kernel_launch(void* const* d_in, const int* in_sizes, int n_in,
                              void* d_out, int out_size, void* d_ws, size_t ws_size,
                              hipStream_t stream) {
    const float* x = (const float*)d_in[0];
    const int* edge_index = (const int*)d_in[1];
    const float* W = (const float*)d_in[2];
    const float* b = (const float*)d_in[3];
    float* out = (float*)d_out;

    const int N = N_NODES;
    const int E = in_sizes[1] / 2;

    const int* row = edge_index;        // source
    const int* col = edge_index + E;    // destination

    char* ws = (char*)d_ws;
    size_t off = 0;
    int* cnt = (int*)(ws + off);             off = align16(off + (size_t)N * 4);
    float* dinv = (float*)(ws + off);        off = align16(off + (size_t)N * 4);
    int* row_start = (int*)(ws + off);       off = align16(off + (size_t)(N + 1) * 4);
    int* cursor = (int*)(ws + off);          off = align16(off + (size_t)N * 4);
    int* partials = (int*)(ws + off);        off = align16(off + 512 * 4);
    unsigned* csr = (unsigned*)(ws + off);   off = align16(off + (size_t)E * 4);
    unsigned short* y0 = (unsigned short*)(ws + off); off = align16(off + (size_t)N * OUT_C * 2);
    unsigned short* y1 = (unsigned short*)(ws + off); off = align16(off + (size_t)N * OUT_C * 2);

    const int B = 256;
    const int nb_n256 = (N + B - 1) / B;
    const int nb_e = (E + B - 1) / B;          // 3125
    const int nb_scan = (N + SCAN_B - 1) / SCAN_B;  // 196
    const int nb_lin = (N + 63) / 64;          // 1563

    // ---- CSR metadata ----
    zero_int_kernel<<<nb_n256, B, 0, stream>>>(cnt, N);
    count_kernel<<<nb_e, B, 0, stream>>>(col, cnt, E);
    scan_pass1_kernel<<<nb_scan, SCAN_B, 0, stream>>>(cnt, partials, N);
    scan23_kernel<<<nb_scan, SCAN_B, 0, stream>>>(cnt, partials, row_start, cursor, dinv, N, nb_scan);

    // ---- fused: csr_fill + linear (independent; overlap) ----
    fill_linear_kernel<<<nb_e + nb_lin, B, 0, stream>>>(row, col, dinv, cursor, csr, E, nb_e,
                                                        x, W, y0, N);

    // ---- hop 1 ----
    gather_kernel<false><<<(N + 3) / 4, B, 0, stream>>>(y0, y1, nullptr, row_start, csr, dinv, b, N);

    // ---- hop 2 + bias + sigmoid ----
    gather_kernel<true><<<(N + 3) / 4, B, 0, stream>>>(y1, nullptr, out, row_start, csr, dinv, b, N);
}